// Round 5
// baseline (260.268 us; speedup 1.0000x reference)
//
#include <hip/hip_runtime.h>

#define B_ 512
#define T_ 512
#define I_ 64
#define H_ 128
#define CHUNK 64
#define NCHUNK (T_ / CHUNK)

typedef float4 f4;

// 2*log2(e): accumulate c = 2*log2e*(w.h + bias) so tanh = 1 - 2/(2^c + 1).
#define K2 2.885390081777927f

template <int CTRL, int BANK>
__device__ __forceinline__ float dppf(float x) {
    return __int_as_float(__builtin_amdgcn_update_dpp(
        0, __float_as_int(x), CTRL, 0xF, BANK, true));
}

__device__ __forceinline__ void gload_lds16(const float* g, float* l) {
    __builtin_amdgcn_global_load_lds(
        (const __attribute__((address_space(1))) unsigned int*)g,
        (__attribute__((address_space(3))) unsigned int*)l, 16, 0, 0);
}

// v_fmac with "v" constraints: weights must be ArchVGPR-resident at each use,
// making AGPR parking (v_accvgpr_read per use) unprofitable for the allocator.
#define AFMA(a, x, w) asm("v_fmac_f32 %0, %2, %3" : "=v"(a) : "0"(a), "v"(x), "v"(w))
#define FMA4A(A, X, W)            \
    AFMA(A.x, (X).x, (W).x);      \
    AFMA(A.y, (X).y, (W).y);      \
    AFMA(A.z, (X).z, (W).z);      \
    AFMA(A.w, (X).w, (W).w)
#define MUL4(A, X, W)             \
    A.x = (X).x * (W).x;          \
    A.y = (X).y * (W).y;          \
    A.z = (X).z * (W).z;          \
    A.w = (X).w * (W).w

__global__ __launch_bounds__(512) __attribute__((amdgpu_waves_per_eu(4, 4)))
void rnn_kernel(const float* __restrict__ token,
                const float* __restrict__ W_ih,
                const float* __restrict__ W_hh,
                const float* __restrict__ b_ih,
                const float* __restrict__ b_hh,
                const float* __restrict__ W_lin,
                const float* __restrict__ b_lin,
                float* __restrict__ out)
{
    // tok_l: step tt has 16 f4 slots; slot (m2*8+e) holds tok[tt*64 + e*8 + m2*4 ..+3]
    // h_l:   2 buffers x 32 f4; slot (m*8+e) holds h[e*16 + m*4 ..+3]
    // (both verified in round 4: a phase reads 8 consecutive slots -> conflict-free)
    __shared__ f4 tok_l[2][CHUNK * 16];   // 32 KB
    __shared__ f4 h_l[64];                // 1 KB (two 512B buffers)

    const int tid = threadIdx.x;
    const int e   = tid & 7;          // K-eighth
    const int G   = tid >> 3;         // output-pair id 0..63
    const int b   = blockIdx.x;

    // ---- weights (x K2): 2 outputs x eighth-K -> 48 floats ----
    f4 wh0[4], wh1[4], wi0[2], wi1[2];
    {
        const f4* r0 = (const f4*)(W_hh + (2 * G) * H_ + e * 16);
        const f4* r1 = (const f4*)(W_hh + (2 * G + 1) * H_ + e * 16);
#pragma unroll
        for (int m = 0; m < 4; ++m) {
            f4 a = r0[m], c = r1[m];
            wh0[m].x = a.x * K2; wh0[m].y = a.y * K2; wh0[m].z = a.z * K2; wh0[m].w = a.w * K2;
            wh1[m].x = c.x * K2; wh1[m].y = c.y * K2; wh1[m].z = c.z * K2; wh1[m].w = c.w * K2;
        }
        const f4* i0 = (const f4*)(W_ih + (2 * G) * I_ + e * 8);
        const f4* i1 = (const f4*)(W_ih + (2 * G + 1) * I_ + e * 8);
#pragma unroll
        for (int m = 0; m < 2; ++m) {
            f4 a = i0[m], c = i1[m];
            wi0[m].x = a.x * K2; wi0[m].y = a.y * K2; wi0[m].z = a.z * K2; wi0[m].w = a.w * K2;
            wi1[m].x = c.x * K2; wi1[m].y = c.y * K2; wi1[m].z = c.z * K2; wi1[m].w = c.w * K2;
        }
    }
    const int   jsel  = 2 * G + (e & 1);
    const float bias2 = K2 * (b_ih[jsel] + b_hh[jsel]);
    const int   wloc  = ((jsel >> 2) & 3) * 32 + (jsel >> 4) * 4 + (jsel & 3);
    const bool  writer = (e < 2);

    const float* tok_row = token + (size_t)b * T_ * I_;

    // Pre-swizzled global source offsets for staging (loop-invariant).
    const int S0 = tid, S1 = 512 + tid;
    const int so0 = (S0 >> 4) * 64 + (S0 & 7) * 8 + ((S0 >> 3) & 1) * 4;
    const int so1 = (S1 >> 4) * 64 + (S1 & 7) * 8 + ((S1 >> 3) & 1) * 4;

    // ---- stage chunk 0 ----
    gload_lds16(tok_row + so0, (float*)&tok_l[0][S0]);
    gload_lds16(tok_row + so1, (float*)&tok_l[0][S1]);
    if (tid < H_) ((float*)h_l)[tid] = 0.0f;
    asm volatile("s_waitcnt vmcnt(0) lgkmcnt(0)" ::: "memory");
    asm volatile("s_barrier" ::: "memory");

    const char* hbase = (const char*)h_l;
    const char* tbase = (const char*)tok_l;
    unsigned roff = 0;

#pragma unroll 1
    for (int c = 0; c < NCHUNK; ++c) {
        const int cb = c & 1;
        if (c + 1 < NCHUNK) {   // prefetch next chunk; vmcnt stays in flight 64 steps
            const float* g = tok_row + (size_t)(c + 1) * CHUNK * I_;
            float* dst = (float*)(tbase + (cb ^ 1) * (CHUNK * 16 * 16));
            gload_lds16(g + so0, dst + S0 * 4);
            gload_lds16(g + so1, dst + S1 * 4);
        }
        unsigned toff = (unsigned)cb * (CHUNK * 16 * 16);

#pragma unroll 1
        for (int tt = 0; tt < CHUNK; ++tt) {
            const f4* tv  = (const f4*)(tbase + toff);
            const f4* hrd = (const f4*)(hbase + roff);
            f4 t0 = tv[e],       t1 = tv[8 + e];
            f4 h0 = hrd[e],      h1 = hrd[8 + e];
            f4 h2 = hrd[16 + e], h3 = hrd[24 + e];

            f4 A0, A1;
            MUL4(A0, t0, wi0[0]);  MUL4(A1, t0, wi1[0]);
            FMA4A(A0, t1, wi0[1]); FMA4A(A1, t1, wi1[1]);
            FMA4A(A0, h0, wh0[0]); FMA4A(A1, h0, wh1[0]);
            FMA4A(A0, h1, wh0[1]); FMA4A(A1, h1, wh1[1]);
            FMA4A(A0, h2, wh0[2]); FMA4A(A1, h2, wh1[2]);
            FMA4A(A0, h3, wh0[3]); FMA4A(A1, h3, wh1[3]);

            float p0 = (A0.x + A0.y) + (A0.z + A0.w);
            float p1 = (A1.x + A1.y) + (A1.z + A1.w);
            // 8-lane reduce (verified in round 4)
            p0 += dppf<0xB1, 0xF>(p0);
            p1 += dppf<0xB1, 0xF>(p1);
            float cc = (e & 1) ? p1 : p0;
            cc += dppf<0x4E, 0xF>(cc);
            float d1 = dppf<0x104, 0x5>(cc);
            float d2 = dppf<0x114, 0xA>(cc);
            cc = cc + d1 + d2;
            // tanh: c already = 2*log2e*x  ->  hn = 1 - 2/(2^c + 1)
            float ex;
            asm("v_exp_f32 %0, %1" : "=v"(ex) : "v"(cc + bias2));
            float r = __builtin_amdgcn_rcpf(ex + 1.0f);
            float hn = 1.0f - (r + r);

            float* hwr = (float*)(hbase + (roff ^ 512));
            if (writer) hwr[wloc] = hn;
            asm volatile("s_waitcnt lgkmcnt(0)" ::: "memory");
            asm volatile("s_barrier" ::: "memory");
            roff ^= 512;
            toff += 16 * 16;   // next step's 16 f4 slots
        }

        if (c + 1 < NCHUNK) {   // prefetched buffer must be resident for next chunk
            asm volatile("s_waitcnt vmcnt(0)" ::: "memory");
            asm volatile("s_barrier" ::: "memory");
        }
    }

    // ---- linear head on buffer 0 (512 steps -> roff back to 0) ----
    if (tid < 64) {
        const int j0 = tid, j1 = tid + 64;
        const int l0 = ((j0 >> 2) & 3) * 32 + (j0 >> 4) * 4 + (j0 & 3);
        const int l1 = ((j1 >> 2) & 3) * 32 + (j1 >> 4) * 4 + (j1 & 3);
        float p = ((const float*)h_l)[l0] * W_lin[j0]
                + ((const float*)h_l)[l1] * W_lin[j1];
#pragma unroll
        for (int off = 32; off; off >>= 1) p += __shfl_down(p, off);
        if (tid == 0) out[b] = p + b_lin[0];
    }
}

extern "C" void kernel_launch(void* const* d_in, const int* in_sizes, int n_in,
                              void* d_out, int out_size, void* d_ws, size_t ws_size,
                              hipStream_t stream) {
    const float* token = (const float*)d_in[0];
    const float* W_ih  = (const float*)d_in[1];
    const float* W_hh  = (const float*)d_in[2];
    const float* b_ih  = (const float*)d_in[3];
    const float* b_hh  = (const float*)d_in[4];
    const float* W_lin = (const float*)d_in[5];
    const float* b_lin = (const float*)d_in[6];
    float* out = (float*)d_out;

    hipLaunchKernelGGL(rnn_kernel, dim3(B_), dim3(512), 0, stream,
                       token, W_ih, W_hh, b_ih, b_hh, W_lin, b_lin, out);
}

// Round 7
// 230.313 us; speedup vs baseline: 1.1301x; 1.1301x over previous
//
#include <hip/hip_runtime.h>

#define B_ 512
#define T_ 512
#define I_ 64
#define H_ 128
#define CHUNK 64
#define NCHUNK (T_ / CHUNK)

// LDS byte layout (single __shared__ block)
#define TOKBYTES 16384              // 64 steps * 16 f4 slots * 16B
#define HB0      (2 * TOKBYTES)     // 32768: h ping buffer (512B)
#define HB1      (HB0 + 512)        // 33280: h pong buffer
#define DUMMY    (HB1 + 512)        // 33792: dump slots for non-writer lanes
#define LDS_SZ   (DUMMY + 256)      // 34048 B total

__device__ __forceinline__ void gload_lds16(const float* g, void* l) {
    __builtin_amdgcn_global_load_lds(
        (const __attribute__((address_space(1))) unsigned int*)g,
        (__attribute__((address_space(3))) unsigned int*)l, 16, 0, 0);
}

// ---- explicit-register asm helpers ----
#define FM(a, x, w) "v_fmac_f32 v" #a ", v" #x ", v" #w "\n\t"
#define SC(n) "v_mul_f32 v" #n ", 0x4038aa3b, v" #n "\n\t"   // *= 2*log2(e)

#define CLOBS \
    "v48","v49","v50","v51","v52","v53","v54","v55","v56","v57","v58","v59", \
    "v60","v61","v62","v63","v64","v65","v66","v67","v68","v69","v70","v71", \
    "v72","v73","v74","v75","v76","v77","v78","v79","v80","v81","v82","v83", \
    "v84","v85","v86","v87","v88","v89","v90","v91","v92","v93","v94","v95", \
    "v96","v97","v98","v99","v100","v101","v102","v103","v104","v105","v106", \
    "v107","v108","v109","v110","v111","v112","v113","v114","v115","v116", \
    "v117","v118","v119","v120","v121","v122","v123","v124","v125","v126", \
    "v127","memory"

// One RNN step. Register map:
//   wh0 v80-95, wh1 v96-111, wi0 v112-119, wi1 v120-127   (persistent)
//   A0 v48-51, A1 v52-55, t0 v56-59, t1 v60-63, h v64-79  (scratch)
// DPP hazard rule (GCNHazardRecognizer): DPP VGPR src needs 2 wait states
// after a VALU write of that reg -> s_nop 1 before each close DPP.
// Trans (v_exp/v_rcp) -> consumer: 1 wait state -> s_nop 0.
#define RNN_STEP(TOKA, HRD, HWR, BA, BB, PAR)                                 \
    asm volatile(                                                             \
        "ds_read_b128 v[56:59], %0\n\t"                                       \
        "ds_read_b128 v[60:63], %0 offset:128\n\t"                            \
        "ds_read_b128 v[64:67], %1\n\t"                                       \
        "ds_read_b128 v[68:71], %1 offset:128\n\t"                            \
        "ds_read_b128 v[72:75], %1 offset:256\n\t"                            \
        "ds_read_b128 v[76:79], %1 offset:384\n\t"                            \
        "v_add_u32 %0, 256, %0\n\t"                                           \
        "s_waitcnt lgkmcnt(4)\n\t"                                            \
        "v_fma_f32 v48, v56, v112, %3\n\t"                                    \
        "v_mul_f32 v49, v57, v113\n\t"                                        \
        "v_mul_f32 v50, v58, v114\n\t"                                        \
        "v_mul_f32 v51, v59, v115\n\t"                                        \
        "v_fma_f32 v52, v56, v120, %4\n\t"                                    \
        "v_mul_f32 v53, v57, v121\n\t"                                        \
        "v_mul_f32 v54, v58, v122\n\t"                                        \
        "v_mul_f32 v55, v59, v123\n\t"                                        \
        FM(48,60,116) FM(49,61,117) FM(50,62,118) FM(51,63,119)               \
        FM(52,60,124) FM(53,61,125) FM(54,62,126) FM(55,63,127)               \
        "s_waitcnt lgkmcnt(2)\n\t"                                            \
        FM(48,64,80)  FM(49,65,81)  FM(50,66,82)  FM(51,67,83)                \
        FM(52,64,96)  FM(53,65,97)  FM(54,66,98)  FM(55,67,99)                \
        FM(48,68,84)  FM(49,69,85)  FM(50,70,86)  FM(51,71,87)                \
        FM(52,68,100) FM(53,69,101) FM(54,70,102) FM(55,71,103)               \
        "s_waitcnt lgkmcnt(0)\n\t"                                            \
        FM(48,72,88)  FM(49,73,89)  FM(50,74,90)  FM(51,75,91)                \
        FM(52,72,104) FM(53,73,105) FM(54,74,106) FM(55,75,107)               \
        FM(48,76,92)  FM(49,77,93)  FM(50,78,94)  FM(51,79,95)                \
        FM(52,76,108) FM(53,77,109) FM(54,78,110) FM(55,79,111)               \
        "v_add_f32 v48, v48, v49\n\t"                                         \
        "v_add_f32 v50, v50, v51\n\t"                                         \
        "v_add_f32 v52, v52, v53\n\t"                                         \
        "v_add_f32 v54, v54, v55\n\t"                                         \
        "v_add_f32 v48, v48, v50\n\t"                                         \
        "v_add_f32 v52, v52, v54\n\t"                                         \
        "s_nop 1\n\t"                                                         \
        "v_add_f32 v48, v48, v48 quad_perm:[1,0,3,2] row_mask:0xf bank_mask:0xf\n\t" \
        "v_add_f32 v52, v52, v52 quad_perm:[1,0,3,2] row_mask:0xf bank_mask:0xf\n\t" \
        "v_cndmask_b32 v49, v48, v52, %5\n\t"                                 \
        "s_nop 1\n\t"                                                         \
        "v_add_f32 v49, v49, v49 quad_perm:[2,3,0,1] row_mask:0xf bank_mask:0xf\n\t" \
        "s_nop 1\n\t"                                                         \
        "v_add_f32 v49, v49, v49 row_shl:4 row_mask:0xf bank_mask:0x5\n\t"    \
        "s_nop 1\n\t"                                                         \
        "v_exp_f32 v49, v49\n\t"                                              \
        "s_nop 0\n\t"                                                         \
        "v_add_f32 v49, 1.0, v49\n\t"                                         \
        "v_rcp_f32 v50, v49\n\t"                                              \
        "s_nop 0\n\t"                                                         \
        "v_fma_f32 v49, v50, -2.0, 1.0\n\t"                                   \
        "ds_write_b32 %2, v49\n\t"                                            \
        "s_waitcnt lgkmcnt(0)\n\t"                                            \
        "s_barrier"                                                           \
        : "+v"(TOKA)                                                          \
        : "v"(HRD), "v"(HWR), "v"(BA), "v"(BB), "s"(PAR)                      \
        : CLOBS)

__global__ __launch_bounds__(512) __attribute__((amdgpu_waves_per_eu(4, 4)))
void rnn_kernel(const float* __restrict__ token,
                const float* __restrict__ W_ih,
                const float* __restrict__ W_hh,
                const float* __restrict__ b_ih,
                const float* __restrict__ b_hh,
                const float* __restrict__ W_lin,
                const float* __restrict__ b_lin,
                float* __restrict__ out)
{
    __shared__ __align__(16) char lds[LDS_SZ];
    const unsigned lb =
        (unsigned)(uintptr_t)(__attribute__((address_space(3))) char*)lds;

    const int tid = threadIdx.x;
    const int e   = tid & 7;          // K-eighth
    const int G   = tid >> 3;         // output-pair id 0..63
    const int b   = blockIdx.x;
    const int j0  = 2 * G, j1 = 2 * G + 1;

    // ---- load + scale weights into fixed v80-v127 ----
    {
        const float* pA = W_hh + j0 * H_ + e * 16;
        const float* pB = W_hh + j1 * H_ + e * 16;
        const float* pC = W_ih + j0 * I_ + e * 8;
        const float* pD = W_ih + j1 * I_ + e * 8;
        asm volatile(
            "global_load_dwordx4 v[80:83], %0, off\n\t"
            "global_load_dwordx4 v[84:87], %0, off offset:16\n\t"
            "global_load_dwordx4 v[88:91], %0, off offset:32\n\t"
            "global_load_dwordx4 v[92:95], %0, off offset:48\n\t"
            "global_load_dwordx4 v[96:99], %1, off\n\t"
            "global_load_dwordx4 v[100:103], %1, off offset:16\n\t"
            "global_load_dwordx4 v[104:107], %1, off offset:32\n\t"
            "global_load_dwordx4 v[108:111], %1, off offset:48\n\t"
            "global_load_dwordx4 v[112:115], %2, off\n\t"
            "global_load_dwordx4 v[116:119], %2, off offset:16\n\t"
            "global_load_dwordx4 v[120:123], %3, off\n\t"
            "global_load_dwordx4 v[124:127], %3, off offset:16\n\t"
            "s_waitcnt vmcnt(0)\n\t"
            SC(80) SC(81) SC(82) SC(83) SC(84) SC(85) SC(86) SC(87)
            SC(88) SC(89) SC(90) SC(91) SC(92) SC(93) SC(94) SC(95)
            SC(96) SC(97) SC(98) SC(99) SC(100) SC(101) SC(102) SC(103)
            SC(104) SC(105) SC(106) SC(107) SC(108) SC(109) SC(110) SC(111)
            SC(112) SC(113) SC(114) SC(115) SC(116) SC(117) SC(118) SC(119)
            SC(120) SC(121) SC(122) SC(123) SC(124) SC(125) SC(126) SC(127)
            :: "v"(pA), "v"(pB), "v"(pC), "v"(pD) : CLOBS);
    }

    // bias pre-seeded per lane, /8 (exact) since 8 lanes contribute it
    const float biasA = (b_ih[j0] + b_hh[j0]) * (2.885390081777927f / 8.0f);
    const float biasB = (b_ih[j1] + b_hh[j1]) * (2.885390081777927f / 8.0f);
    const unsigned long long par = 0xAAAAAAAAAAAAAAAAULL;  // odd lanes -> p1

    // h write location: h[j] lives at float offset ((j>>2)&3)*32+(j>>4)*4+(j&3)
    const int  jsel   = 2 * G + (e & 1);
    const int  wloc   = ((jsel >> 2) & 3) * 32 + (jsel >> 4) * 4 + (jsel & 3);
    const bool writer = (e < 2);
    const unsigned dmy = lb + DUMMY + (tid & 63) * 4;
    const unsigned hw0 = writer ? (lb + HB1 + wloc * 4) : dmy;  // buf0 -> buf1
    const unsigned hw1 = writer ? (lb + HB0 + wloc * 4) : dmy;  // buf1 -> buf0
    const unsigned hr0 = lb + HB0 + e * 16;
    const unsigned hr1 = lb + HB1 + e * 16;

    const float* tok_row = token + (size_t)b * T_ * I_;
    // pre-swizzled global float offsets (layout slot S=(tt*16 + m2*8 + e))
    const int S0 = tid, S1 = 512 + tid;
    const int so0 = (S0 >> 4) * 64 + (S0 & 7) * 8 + ((S0 >> 3) & 1) * 4;
    const int so1 = (S1 >> 4) * 64 + (S1 & 7) * 8 + ((S1 >> 3) & 1) * 4;

    // ---- stage chunk 0; zero h buf0 ----
    gload_lds16(tok_row + so0, lds + S0 * 16);
    gload_lds16(tok_row + so1, lds + S1 * 16);
    if (tid < H_) *(float*)(lds + HB0 + tid * 4) = 0.0f;
    asm volatile("s_waitcnt vmcnt(0) lgkmcnt(0)\n\ts_barrier" ::: "memory");

#pragma unroll 1
    for (int c = 0; c < NCHUNK; ++c) {
        const int cb = c & 1;
        const bool has_next = (c + 1 < NCHUNK);
        if (has_next) {  // async prefetch; stays in flight under the 64 steps
            const float* g = tok_row + (size_t)(c + 1) * CHUNK * I_;
            char* dst = lds + (cb ^ 1) * TOKBYTES;
            gload_lds16(g + so0, dst + S0 * 16);
            gload_lds16(g + so1, dst + S1 * 16);
        }
        unsigned toka = lb + cb * TOKBYTES + e * 16;

#pragma unroll 1
        for (int tt = 0; tt < CHUNK; tt += 2) {
            RNN_STEP(toka, hr0, hw0, biasA, biasB, par);   // buf0 -> buf1
            RNN_STEP(toka, hr1, hw1, biasA, biasB, par);   // buf1 -> buf0
        }

        if (has_next) {  // prefetched buffer must be resident before next chunk
            asm volatile("s_waitcnt vmcnt(0)\n\ts_barrier" ::: "memory");
        }
    }

    // ---- linear head on h buf0 (512 steps even -> final h in buf0) ----
    if (tid < 64) {
        const int a0 = tid, a1 = tid + 64;
        const int l0 = ((a0 >> 2) & 3) * 32 + (a0 >> 4) * 4 + (a0 & 3);
        const int l1 = ((a1 >> 2) & 3) * 32 + (a1 >> 4) * 4 + (a1 & 3);
        float p = *(const float*)(lds + HB0 + l0 * 4) * W_lin[a0]
                + *(const float*)(lds + HB0 + l1 * 4) * W_lin[a1];
#pragma unroll
        for (int off = 32; off; off >>= 1) p += __shfl_down(p, off);
        if (tid == 0) out[b] = p + b_lin[0];
    }
}

extern "C" void kernel_launch(void* const* d_in, const int* in_sizes, int n_in,
                              void* d_out, int out_size, void* d_ws, size_t ws_size,
                              hipStream_t stream) {
    const float* token = (const float*)d_in[0];
    const float* W_ih  = (const float*)d_in[1];
    const float* W_hh  = (const float*)d_in[2];
    const float* b_ih  = (const float*)d_in[3];
    const float* b_hh  = (const float*)d_in[4];
    const float* W_lin = (const float*)d_in[5];
    const float* b_lin = (const float*)d_in[6];
    float* out = (float*)d_out;

    hipLaunchKernelGGL(rnn_kernel, dim3(B_), dim3(512), 0, stream,
                       token, W_ih, W_hh, b_ih, b_hh, W_lin, b_lin, out);
}

// Round 8
// 206.798 us; speedup vs baseline: 1.2586x; 1.1137x over previous
//
#include <hip/hip_runtime.h>

#define B_ 512
#define T_ 512
#define I_ 64
#define H_ 128
#define CHUNK 64
#define NCHUNK (T_ / CHUNK)

// LDS byte layout
#define TOKBYTES 16384              // 64 steps * 64 floats * 4B (LINEAR)
#define HB0      (2 * TOKBYTES)     // 32768: h ping (512B)
#define HB1      (HB0 + 512)        // 33280: h pong
#define DUMMY    (HB1 + 512)        // 33792: dump for non-writer lanes
#define LDS_SZ   (DUMMY + 256)

__device__ __forceinline__ void gload_lds16(const float* g, void* l) {
    __builtin_amdgcn_global_load_lds(
        (const __attribute__((address_space(1))) unsigned int*)g,
        (__attribute__((address_space(3))) unsigned int*)l, 16, 0, 0);
}

#define FM(a, x, w) "v_fmac_f32 v" #a ", v" #x ", v" #w "\n\t"
#define SC(n) "v_mul_f32 v" #n ", 0x4038aa3b, v" #n "\n\t"   // *= 2*log2(e)

#define CLOBS \
    "v48","v49","v50","v51","v52","v53","v54","v55","v56","v57","v58","v59", \
    "v60","v61","v62","v63","v64","v65","v66","v67","v68","v69","v70","v71", \
    "v72","v73","v74","v75","v76","v77","v78","v79","v80","v81","v82","v83", \
    "v84","v85","v86","v87","v88","v89","v90","v91","v92","v93","v94","v95", \
    "v96","v97","v98","v99","v100","v101","v102","v103","v104","v105","v106", \
    "v107","v108","v109","v110","v111","v112","v113","v114","v115","v116", \
    "v117","v118","v119","v120","v121","v122","v123","v124","v125","v126", \
    "v127","memory"

// Register map: wh j0..j3 = v80-87/88-95/96-103/104-111; wi j0..j3 = v112-115/
// 116-119/120-123/124-127. Scratch: A0-A3 v48-51, temps v52-55, tok v56-59,
// h v64-71. s=16: lane e=tid&15 owns h[e*8..+7], tok[e*4..+3]; r=4 outputs.
// DPP hazard: 2 wait states after VALU write of a DPP source (round-7-proven).
#define RNN_STEP(TOKA, HRD, HWR, BA, BB, BC, BD, M1, M2)                      \
    asm volatile(                                                             \
        "ds_read_b128 v[56:59], %0\n\t"                                       \
        "ds_read_b128 v[64:67], %1\n\t"                                       \
        "ds_read_b128 v[68:71], %1 offset:256\n\t"                            \
        "v_add_u32 %0, 256, %0\n\t"                                           \
        "s_waitcnt lgkmcnt(2)\n\t"                                            \
        "v_fma_f32 v48, v56, v112, %3\n\t"                                    \
        "v_fma_f32 v49, v56, v116, %4\n\t"                                    \
        "v_fma_f32 v50, v56, v120, %5\n\t"                                    \
        "v_fma_f32 v51, v56, v124, %6\n\t"                                    \
        FM(48,57,113) FM(49,57,117) FM(50,57,121) FM(51,57,125)               \
        FM(48,58,114) FM(49,58,118) FM(50,58,122) FM(51,58,126)               \
        FM(48,59,115) FM(49,59,119) FM(50,59,123) FM(51,59,127)               \
        "s_waitcnt lgkmcnt(1)\n\t"                                            \
        FM(48,64,80) FM(49,64,88) FM(50,64,96)  FM(51,64,104)                 \
        FM(48,65,81) FM(49,65,89) FM(50,65,97)  FM(51,65,105)                 \
        FM(48,66,82) FM(49,66,90) FM(50,66,98)  FM(51,66,106)                 \
        FM(48,67,83) FM(49,67,91) FM(50,67,99)  FM(51,67,107)                 \
        "s_waitcnt lgkmcnt(0)\n\t"                                            \
        FM(48,68,84) FM(49,68,92) FM(50,68,100) FM(51,68,108)                 \
        FM(48,69,85) FM(49,69,93) FM(50,69,101) FM(51,69,109)                 \
        FM(48,70,86) FM(49,70,94) FM(50,70,102) FM(51,70,110)                 \
        FM(48,71,87) FM(49,71,95) FM(50,71,103) FM(51,71,111)                 \
        "s_nop 1\n\t"                                                         \
        "v_add_f32 v48, v48, v48 quad_perm:[1,0,3,2] row_mask:0xf bank_mask:0xf\n\t" \
        "v_add_f32 v49, v49, v49 quad_perm:[1,0,3,2] row_mask:0xf bank_mask:0xf\n\t" \
        "v_add_f32 v50, v50, v50 quad_perm:[1,0,3,2] row_mask:0xf bank_mask:0xf\n\t" \
        "v_add_f32 v51, v51, v51 quad_perm:[1,0,3,2] row_mask:0xf bank_mask:0xf\n\t" \
        "v_cndmask_b32 v52, v48, v49, %7\n\t"                                 \
        "v_cndmask_b32 v53, v50, v51, %7\n\t"                                 \
        "s_nop 0\n\t"                                                         \
        "v_add_f32 v52, v52, v52 quad_perm:[2,3,0,1] row_mask:0xf bank_mask:0xf\n\t" \
        "v_add_f32 v53, v53, v53 quad_perm:[2,3,0,1] row_mask:0xf bank_mask:0xf\n\t" \
        "v_cndmask_b32 v54, v52, v53, %8\n\t"                                 \
        "s_nop 1\n\t"                                                         \
        "v_add_f32 v54, v54, v54 row_shl:8 row_mask:0xf bank_mask:0x3\n\t"    \
        "s_nop 1\n\t"                                                         \
        "v_add_f32 v54, v54, v54 row_shl:4 row_mask:0xf bank_mask:0x1\n\t"    \
        "s_nop 1\n\t"                                                         \
        "v_exp_f32 v54, v54\n\t"                                              \
        "s_nop 0\n\t"                                                         \
        "v_add_f32 v54, 1.0, v54\n\t"                                         \
        "v_rcp_f32 v55, v54\n\t"                                              \
        "s_nop 0\n\t"                                                         \
        "v_fma_f32 v54, v55, -2.0, 1.0\n\t"                                   \
        "ds_write_b32 %2, v54\n\t"                                            \
        "s_waitcnt lgkmcnt(0)\n\t"                                            \
        "s_barrier"                                                           \
        : "+v"(TOKA)                                                          \
        : "v"(HRD), "v"(HWR), "v"(BA), "v"(BB), "v"(BC), "v"(BD),             \
          "s"(M1), "s"(M2)                                                    \
        : CLOBS)

__global__ __launch_bounds__(512) __attribute__((amdgpu_waves_per_eu(4, 4)))
void rnn_kernel(const float* __restrict__ token,
                const float* __restrict__ W_ih,
                const float* __restrict__ W_hh,
                const float* __restrict__ b_ih,
                const float* __restrict__ b_hh,
                const float* __restrict__ W_lin,
                const float* __restrict__ b_lin,
                float* __restrict__ out)
{
    __shared__ __align__(16) char lds[LDS_SZ];
    const unsigned lb =
        (unsigned)(uintptr_t)(__attribute__((address_space(3))) char*)lds;

    const int tid = threadIdx.x;
    const int e   = tid & 15;         // K-sixteenth
    const int G   = tid >> 4;         // output-quad id 0..31
    const int b   = blockIdx.x;
    const int jb  = 4 * G;

    // ---- weights into fixed v80-v127 (rows 512B / 256B apart) ----
    {
        const float* pWh = W_hh + jb * H_ + e * 8;
        const float* pWi = W_ih + jb * I_ + e * 4;
        asm volatile(
            "global_load_dwordx4 v[80:83],   %0, off\n\t"
            "global_load_dwordx4 v[84:87],   %0, off offset:16\n\t"
            "global_load_dwordx4 v[88:91],   %0, off offset:512\n\t"
            "global_load_dwordx4 v[92:95],   %0, off offset:528\n\t"
            "global_load_dwordx4 v[96:99],   %0, off offset:1024\n\t"
            "global_load_dwordx4 v[100:103], %0, off offset:1040\n\t"
            "global_load_dwordx4 v[104:107], %0, off offset:1536\n\t"
            "global_load_dwordx4 v[108:111], %0, off offset:1552\n\t"
            "global_load_dwordx4 v[112:115], %1, off\n\t"
            "global_load_dwordx4 v[116:119], %1, off offset:256\n\t"
            "global_load_dwordx4 v[120:123], %1, off offset:512\n\t"
            "global_load_dwordx4 v[124:127], %1, off offset:768\n\t"
            "s_waitcnt vmcnt(0)\n\t"
            SC(80) SC(81) SC(82) SC(83) SC(84) SC(85) SC(86) SC(87)
            SC(88) SC(89) SC(90) SC(91) SC(92) SC(93) SC(94) SC(95)
            SC(96) SC(97) SC(98) SC(99) SC(100) SC(101) SC(102) SC(103)
            SC(104) SC(105) SC(106) SC(107) SC(108) SC(109) SC(110) SC(111)
            SC(112) SC(113) SC(114) SC(115) SC(116) SC(117) SC(118) SC(119)
            SC(120) SC(121) SC(122) SC(123) SC(124) SC(125) SC(126) SC(127)
            :: "v"(pWh), "v"(pWi) : CLOBS);
    }

    // biases pre-scaled by K2/16 (16 lanes each contribute the seed; /16 exact)
    const float k16 = 2.885390081777927f / 16.0f;
    const float biasA = (b_ih[jb + 0] + b_hh[jb + 0]) * k16;
    const float biasB = (b_ih[jb + 1] + b_hh[jb + 1]) * k16;
    const float biasC = (b_ih[jb + 2] + b_hh[jb + 2]) * k16;
    const float biasD = (b_ih[jb + 3] + b_hh[jb + 3]) * k16;
    const unsigned long long M1 = 0xAAAAAAAAAAAAAAAAULL;  // lanes with e&1
    const unsigned long long M2 = 0xCCCCCCCCCCCCCCCCULL;  // lanes with e&2

    // h float j at byte (((j>>2)&1)*16 + (j>>3))*16 + (j&3)*4
    const int  jsel   = jb + (e & 3);     // writer lanes e<4 finalize jb+e
    const int  wbyte  = ((((jsel >> 2) & 1) * 16 + (jsel >> 3)) * 16) + (jsel & 3) * 4;
    const bool writer = (e < 4);
    const unsigned dmy = lb + DUMMY + (tid & 63) * 4;
    const unsigned hw0 = writer ? (lb + HB1 + wbyte) : dmy;  // buf0 -> buf1
    const unsigned hw1 = writer ? (lb + HB0 + wbyte) : dmy;  // buf1 -> buf0
    const unsigned hr0 = lb + HB0 + e * 16;
    const unsigned hr1 = lb + HB1 + e * 16;

    const float* tok_row = token + (size_t)b * T_ * I_;
    const int S0 = tid, S1 = 512 + tid;   // f4 slots, LINEAR layout

    // ---- stage chunk 0; zero h buf0 ----
    gload_lds16(tok_row + S0 * 4, lds + S0 * 16);
    gload_lds16(tok_row + S1 * 4, lds + S1 * 16);
    if (tid < H_) *(float*)(lds + HB0 + tid * 4) = 0.0f;
    asm volatile("s_waitcnt vmcnt(0) lgkmcnt(0)\n\ts_barrier" ::: "memory");

#pragma unroll 1
    for (int c = 0; c < NCHUNK; ++c) {
        const int cb = c & 1;
        const bool has_next = (c + 1 < NCHUNK);
        if (has_next) {  // async prefetch; in flight under the 64 steps
            const float* g = tok_row + (size_t)(c + 1) * CHUNK * I_;
            char* dst = lds + (cb ^ 1) * TOKBYTES;
            gload_lds16(g + S0 * 4, dst + S0 * 16);
            gload_lds16(g + S1 * 4, dst + S1 * 16);
        }
        unsigned toka = lb + cb * TOKBYTES + e * 16;

#pragma unroll 1
        for (int tt = 0; tt < CHUNK; tt += 2) {
            RNN_STEP(toka, hr0, hw0, biasA, biasB, biasC, biasD, M1, M2);
            RNN_STEP(toka, hr1, hw1, biasA, biasB, biasC, biasD, M1, M2);
        }

        if (has_next) {
            asm volatile("s_waitcnt vmcnt(0)\n\ts_barrier" ::: "memory");
        }
    }

    // ---- linear head on h buf0 ----
    if (tid < 64) {
        const int a0 = tid, a1 = tid + 64;
        const int l0 = (((a0 >> 2) & 1) * 16 + (a0 >> 3)) * 4 + (a0 & 3);
        const int l1 = (((a1 >> 2) & 1) * 16 + (a1 >> 3)) * 4 + (a1 & 3);
        float p = *(const float*)(lds + HB0 + l0 * 4) * W_lin[a0]
                + *(const float*)(lds + HB0 + l1 * 4) * W_lin[a1];
#pragma unroll
        for (int off = 32; off; off >>= 1) p += __shfl_down(p, off);
        if (tid == 0) out[b] = p + b_lin[0];
    }
}

extern "C" void kernel_launch(void* const* d_in, const int* in_sizes, int n_in,
                              void* d_out, int out_size, void* d_ws, size_t ws_size,
                              hipStream_t stream) {
    const float* token = (const float*)d_in[0];
    const float* W_ih  = (const float*)d_in[1];
    const float* W_hh  = (const float*)d_in[2];
    const float* b_ih  = (const float*)d_in[3];
    const float* b_hh  = (const float*)d_in[4];
    const float* W_lin = (const float*)d_in[5];
    const float* b_lin = (const float*)d_in[6];
    float* out = (float*)d_out;

    hipLaunchKernelGGL(rnn_kernel, dim3(B_), dim3(512), 0, stream,
                       token, W_ih, W_hh, b_ih, b_hh, W_lin, b_lin, out);
}

// Round 9
// 197.974 us; speedup vs baseline: 1.3147x; 1.0446x over previous
//
#include <hip/hip_runtime.h>

#define B_ 512
#define T_ 512
#define I_ 64
#define H_ 128

// LDS: h ping/pong + dummy dump slots only
#define HB0    0
#define HB1    512
#define DUMMY  1024
#define LDS_SZ 1280

#define FM(a, x, w) "v_fmac_f32 v" #a ", v" #x ", v" #w "\n\t"
#define SC(n) "v_mul_f32 v" #n ", 0x4038aa3b, v" #n "\n\t"   // *= 2*log2(e)

#define CLOBS \
    "v48","v49","v50","v51","v52","v53","v54","v55","v56","v57","v58","v59", \
    "v60","v61","v62","v63","v64","v65","v66","v67","v68","v69","v70","v71", \
    "v72","v73","v74","v75","v76","v77","v78","v79","v80","v81","v82","v83", \
    "v84","v85","v86","v87","v88","v89","v90","v91","v92","v93","v94","v95", \
    "v96","v97","v98","v99","v100","v101","v102","v103","v104","v105","v106", \
    "v107","v108","v109","v110","v111","v112","v113","v114","v115","v116", \
    "v117","v118","v119","v120","v121","v122","v123","v124","v125","v126", \
    "v127","memory"

// Register map:
//   weights: wh j0..j3 = v80-87/88-95/96-103/104-111, wi j0..j3 = v112-115/
//            116-119/120-123/124-127                       (persistent)
//   tok sets: T0 v56-59, T1 v60-63, T2 v64-67, T3 v68-71   (4-deep prefetch)
//   h: v72-79; accums v48-51; temps v52-55
// Step t: tok(t) guaranteed by vmcnt(3); proj from regs fills h ds_read
// latency; reissue tok(t+4) into the freed set. DPP hazard nops as round 8.
#define RNN_STEP(TA, TB, TC, TD, HRD, HWR)                                    \
    asm volatile(                                                             \
        "ds_read_b128 v[72:75], %1\n\t"                                       \
        "ds_read_b128 v[76:79], %1 offset:256\n\t"                            \
        "s_waitcnt vmcnt(3)\n\t"                                              \
        "v_fma_f32 v48, v" #TA ", v112, %3\n\t"                               \
        "v_fma_f32 v49, v" #TA ", v116, %4\n\t"                               \
        "v_fma_f32 v50, v" #TA ", v120, %5\n\t"                               \
        "v_fma_f32 v51, v" #TA ", v124, %6\n\t"                               \
        FM(48,TB,113) FM(49,TB,117) FM(50,TB,121) FM(51,TB,125)               \
        FM(48,TC,114) FM(49,TC,118) FM(50,TC,122) FM(51,TC,126)               \
        FM(48,TD,115) FM(49,TD,119) FM(50,TD,123) FM(51,TD,127)               \
        "global_load_dwordx4 v[" #TA ":" #TD "], %0, %9\n\t"                  \
        "v_add_u32 %0, 0x100, %0\n\t"                                         \
        "v_and_b32 %0, 0x1ffff, %0\n\t"                                       \
        "s_waitcnt lgkmcnt(1)\n\t"                                            \
        FM(48,72,80) FM(49,72,88) FM(50,72,96)  FM(51,72,104)                 \
        FM(48,73,81) FM(49,73,89) FM(50,73,97)  FM(51,73,105)                 \
        FM(48,74,82) FM(49,74,90) FM(50,74,98)  FM(51,74,106)                 \
        FM(48,75,83) FM(49,75,91) FM(50,75,99)  FM(51,75,107)                 \
        "s_waitcnt lgkmcnt(0)\n\t"                                            \
        FM(48,76,84) FM(49,76,92) FM(50,76,100) FM(51,76,108)                 \
        FM(48,77,85) FM(49,77,93) FM(50,77,101) FM(51,77,109)                 \
        FM(48,78,86) FM(49,78,94) FM(50,78,102) FM(51,78,110)                 \
        FM(48,79,87) FM(49,79,95) FM(50,79,103) FM(51,79,111)                 \
        "s_nop 1\n\t"                                                         \
        "v_add_f32 v48, v48, v48 quad_perm:[1,0,3,2] row_mask:0xf bank_mask:0xf\n\t" \
        "v_add_f32 v49, v49, v49 quad_perm:[1,0,3,2] row_mask:0xf bank_mask:0xf\n\t" \
        "v_add_f32 v50, v50, v50 quad_perm:[1,0,3,2] row_mask:0xf bank_mask:0xf\n\t" \
        "v_add_f32 v51, v51, v51 quad_perm:[1,0,3,2] row_mask:0xf bank_mask:0xf\n\t" \
        "v_cndmask_b32 v52, v48, v49, %7\n\t"                                 \
        "v_cndmask_b32 v53, v50, v51, %7\n\t"                                 \
        "s_nop 0\n\t"                                                         \
        "v_add_f32 v52, v52, v52 quad_perm:[2,3,0,1] row_mask:0xf bank_mask:0xf\n\t" \
        "v_add_f32 v53, v53, v53 quad_perm:[2,3,0,1] row_mask:0xf bank_mask:0xf\n\t" \
        "v_cndmask_b32 v54, v52, v53, %8\n\t"                                 \
        "s_nop 1\n\t"                                                         \
        "v_add_f32 v54, v54, v54 row_shl:8 row_mask:0xf bank_mask:0x3\n\t"    \
        "s_nop 1\n\t"                                                         \
        "v_add_f32 v54, v54, v54 row_shl:4 row_mask:0xf bank_mask:0x1\n\t"    \
        "s_nop 1\n\t"                                                         \
        "v_exp_f32 v54, v54\n\t"                                              \
        "s_nop 0\n\t"                                                         \
        "v_add_f32 v54, 1.0, v54\n\t"                                         \
        "v_rcp_f32 v55, v54\n\t"                                              \
        "s_nop 0\n\t"                                                         \
        "v_fma_f32 v54, v55, -2.0, 1.0\n\t"                                   \
        "ds_write_b32 %2, v54\n\t"                                            \
        "s_waitcnt lgkmcnt(0)\n\t"                                            \
        "s_barrier"                                                           \
        : "+v"(voff)                                                          \
        : "v"(HRD), "v"(HWR), "v"(biasA), "v"(biasB), "v"(biasC),             \
          "v"(biasD), "s"(M1), "s"(M2), "s"(sbase)                            \
        : CLOBS)

__global__ __launch_bounds__(512) __attribute__((amdgpu_waves_per_eu(4, 4)))
void rnn_kernel(const float* __restrict__ token,
                const float* __restrict__ W_ih,
                const float* __restrict__ W_hh,
                const float* __restrict__ b_ih,
                const float* __restrict__ b_hh,
                const float* __restrict__ W_lin,
                const float* __restrict__ b_lin,
                float* __restrict__ out)
{
    __shared__ __align__(16) char lds[LDS_SZ];
    const unsigned lb =
        (unsigned)(uintptr_t)(__attribute__((address_space(3))) char*)lds;

    const int tid = threadIdx.x;
    const int e   = tid & 15;         // K-sixteenth
    const int G   = tid >> 4;         // output-quad id 0..31
    const int b   = blockIdx.x;
    const int jb  = 4 * G;

    // ---- weights into fixed v80-v127 (identical to round 8, proven) ----
    {
        const float* pWh = W_hh + jb * H_ + e * 8;
        const float* pWi = W_ih + jb * I_ + e * 4;
        asm volatile(
            "global_load_dwordx4 v[80:83],   %0, off\n\t"
            "global_load_dwordx4 v[84:87],   %0, off offset:16\n\t"
            "global_load_dwordx4 v[88:91],   %0, off offset:512\n\t"
            "global_load_dwordx4 v[92:95],   %0, off offset:528\n\t"
            "global_load_dwordx4 v[96:99],   %0, off offset:1024\n\t"
            "global_load_dwordx4 v[100:103], %0, off offset:1040\n\t"
            "global_load_dwordx4 v[104:107], %0, off offset:1536\n\t"
            "global_load_dwordx4 v[108:111], %0, off offset:1552\n\t"
            "global_load_dwordx4 v[112:115], %1, off\n\t"
            "global_load_dwordx4 v[116:119], %1, off offset:256\n\t"
            "global_load_dwordx4 v[120:123], %1, off offset:512\n\t"
            "global_load_dwordx4 v[124:127], %1, off offset:768\n\t"
            "s_waitcnt vmcnt(0)\n\t"
            SC(80) SC(81) SC(82) SC(83) SC(84) SC(85) SC(86) SC(87)
            SC(88) SC(89) SC(90) SC(91) SC(92) SC(93) SC(94) SC(95)
            SC(96) SC(97) SC(98) SC(99) SC(100) SC(101) SC(102) SC(103)
            SC(104) SC(105) SC(106) SC(107) SC(108) SC(109) SC(110) SC(111)
            SC(112) SC(113) SC(114) SC(115) SC(116) SC(117) SC(118) SC(119)
            SC(120) SC(121) SC(122) SC(123) SC(124) SC(125) SC(126) SC(127)
            :: "v"(pWh), "v"(pWi) : CLOBS);
    }

    // biases pre-scaled by K2/16 (16 lanes each contribute the seed; /16 exact)
    const float k16 = 2.885390081777927f / 16.0f;
    const float biasA = (b_ih[jb + 0] + b_hh[jb + 0]) * k16;
    const float biasB = (b_ih[jb + 1] + b_hh[jb + 1]) * k16;
    const float biasC = (b_ih[jb + 2] + b_hh[jb + 2]) * k16;
    const float biasD = (b_ih[jb + 3] + b_hh[jb + 3]) * k16;
    const unsigned long long M1 = 0xAAAAAAAAAAAAAAAAULL;  // lanes with e&1
    const unsigned long long M2 = 0xCCCCCCCCCCCCCCCCULL;  // lanes with e&2

    // h float j at byte ((j>>2)&1)*256 + (j>>3)*16 + (j&3)*4 (round-8-proven)
    const int  jsel   = jb + (e & 3);
    const int  wbyte  = ((((jsel >> 2) & 1) * 16 + (jsel >> 3)) * 16) + (jsel & 3) * 4;
    const bool writer = (e < 4);
    const unsigned dmy = lb + DUMMY + (tid & 63) * 4;
    const unsigned hw0 = writer ? (lb + HB1 + wbyte) : dmy;  // buf0 -> buf1
    const unsigned hw1 = writer ? (lb + HB0 + wbyte) : dmy;  // buf1 -> buf0
    const unsigned hr0 = lb + HB0 + e * 16;
    const unsigned hr1 = lb + HB1 + e * 16;

    const float* tok_row = token + (size_t)b * T_ * I_;
    const unsigned long long sbase = (unsigned long long)(uintptr_t)tok_row;

    // ---- prologue: issue tok(0..3) into T0..T3; zero h buf0 ----
    {
        const unsigned v0 = e * 16;
        asm volatile(
            "global_load_dwordx4 v[56:59], %0, %1\n\t"
            "global_load_dwordx4 v[60:63], %0, %1 offset:256\n\t"
            "global_load_dwordx4 v[64:67], %0, %1 offset:512\n\t"
            "global_load_dwordx4 v[68:71], %0, %1 offset:768\n\t"
            :: "v"(v0), "s"(sbase) : CLOBS);
    }
    unsigned voff = e * 16 + 1024;    // next issue target: tok(4)
    if (tid < H_) *(float*)(lds + HB0 + tid * 4) = 0.0f;
    asm volatile("s_waitcnt lgkmcnt(0)\n\ts_barrier" ::: "memory");

#pragma unroll 1
    for (int t = 0; t < T_; t += 4) {
        RNN_STEP(56, 57, 58, 59, hr0, hw0);   // t+0: buf0 -> buf1
        RNN_STEP(60, 61, 62, 63, hr1, hw1);   // t+1: buf1 -> buf0
        RNN_STEP(64, 65, 66, 67, hr0, hw0);   // t+2
        RNN_STEP(68, 69, 70, 71, hr1, hw1);   // t+3
    }

    // drain the 4 dangling prefetches (wrapped in-row, harmless)
    asm volatile("s_waitcnt vmcnt(0)" ::: "memory");

    // ---- linear head on h buf0 (512 even steps -> final h in buf0) ----
    if (tid < 64) {
        const int a0 = tid, a1 = tid + 64;
        const int l0 = (((a0 >> 2) & 1) * 16 + (a0 >> 3)) * 4 + (a0 & 3);
        const int l1 = (((a1 >> 2) & 1) * 16 + (a1 >> 3)) * 4 + (a1 & 3);
        float p = *(const float*)(lds + HB0 + l0 * 4) * W_lin[a0]
                + *(const float*)(lds + HB0 + l1 * 4) * W_lin[a1];
#pragma unroll
        for (int off = 32; off; off >>= 1) p += __shfl_down(p, off);
        if (tid == 0) out[b] = p + b_lin[0];
    }
}

extern "C" void kernel_launch(void* const* d_in, const int* in_sizes, int n_in,
                              void* d_out, int out_size, void* d_ws, size_t ws_size,
                              hipStream_t stream) {
    const float* token = (const float*)d_in[0];
    const float* W_ih  = (const float*)d_in[1];
    const float* W_hh  = (const float*)d_in[2];
    const float* b_ih  = (const float*)d_in[3];
    const float* b_hh  = (const float*)d_in[4];
    const float* W_lin = (const float*)d_in[5];
    const float* b_lin = (const float*)d_in[6];
    float* out = (float*)d_out;

    hipLaunchKernelGGL(rnn_kernel, dim3(B_), dim3(512), 0, stream,
                       token, W_ih, W_hh, b_ih, b_hh, W_lin, b_lin, out);
}